// Round 9
// baseline (177.634 us; speedup 1.0000x reference)
//
#include <hip/hip_runtime.h>

// FFLayer: out = relu( (x / (||x||_2 + 1e-4)) @ W^T + b )
// x: [131072,1024] f32, W: [256,1024] f32, b: [256] f32, out: [131072,256] f32
//
// Round 9 = round 8 with 8 waves (512 thr) of 64x64 wave-tiles instead of
// 16 waves of 32x64: LDS read traffic/step 128KB -> 96KB (B-redundancy
// halved), staging geometry/buffers/rotation identical. Counted-vmcnt FIFO
// re-derived: prologue 8; steady 12(even)/8(odd); tail 8,2,0,0.

#define IN_F   1024
#define OUT_F  256
#define BATCH  131072
#define BM     128
#define NKT    32      // BK=32 compute steps
#define EPSV   1e-4f

typedef __attribute__((ext_vector_type(8))) __bf16 bf16x8;
typedef __attribute__((ext_vector_type(4))) __bf16 bf16x4;
typedef __attribute__((ext_vector_type(4))) float  f32x4;

__device__ __forceinline__ void gload_lds16(const void* g, void* lds) {
  __builtin_amdgcn_global_load_lds(
      (const __attribute__((address_space(1))) void*)g,
      (__attribute__((address_space(3))) void*)lds, 16, 0, 0);
}

#define VM_WAIT(N) do { asm volatile("s_waitcnt vmcnt(" #N ")" ::: "memory"); \
                        __builtin_amdgcn_sched_barrier(0); } while (0)

// W (f32 [256][1024]) -> bf16 [256][1024] in d_ws (512 KB)
__global__ void wconv_kernel(const float* __restrict__ W, __bf16* __restrict__ Wb) {
  const int t = blockIdx.x * blockDim.x + threadIdx.x;
  const float4 v = reinterpret_cast<const float4*>(W)[t];
  bf16x4 h;
  h[0] = (__bf16)v.x; h[1] = (__bf16)v.y; h[2] = (__bf16)v.z; h[3] = (__bf16)v.w;
  reinterpret_cast<bf16x4*>(Wb)[t] = h;
}

__global__ __launch_bounds__(512, 2)
void ffl_kernel(const float* __restrict__ x, const __bf16* __restrict__ Wb,
                const float* __restrict__ bias, float* __restrict__ out) {
  // A bufs: 3 x 32KB at 0/32768/65536 (f32, [128 rows][256B], granule-swizzled)
  // B bufs: 4 x 16KB at 98304..163840 (bf16, [256 rows][64B], swizzled)
  // norms: 512B at 163328 (inside B[3], read-done after loop)
  // Epilogue stg [128][260] f32 = 133120B reuses [0,133120).
  __shared__ __align__(16) char smem[163840];
  char* const Ab[3] = {smem, smem + 32768, smem + 65536};
  char* const Bb[4] = {smem + 98304, smem + 114688, smem + 131072, smem + 147456};

  const int tid  = threadIdx.x;
  const int lane = tid & 63;
  const int wave = tid >> 6;     // 8 waves: 2(M) x 4(N), wave tile 64x64
  const int wr   = wave >> 2;    // 0..1, rows wr*64..+63
  const int wc   = wave & 3;     // 0..3, cols wc*64..+63
  const int rm   = lane & 15;
  const int q    = lane >> 4;
  const size_t block_row = (size_t)blockIdx.x * BM;
  const int phg = blockIdx.x & 15;            // K-rotation phase (A-groups)

  // ---- A staging: 4 issues/thread/group. Chunk c=4w+i (1KB = 4 rows x 256B).
  const float* aSrc[4]; int aDst[4];
  #pragma unroll
  for (int i = 0; i < 4; ++i) {
    const int c   = 4 * wave + i;
    const int row = 4 * c + (lane >> 4);
    const int s   = (lane & 15) ^ (row & 7);
    aSrc[i] = x + (block_row + row) * IN_F + s * 4;
    aDst[i] = c * 1024;
  }
  // ---- B staging: 2 issues/thread/step. Chunk c=2w+i (1KB = 16 rows x 64B).
  const __bf16* bSrc[2]; int bDst[2];
  #pragma unroll
  for (int i = 0; i < 2; ++i) {
    const int c    = 2 * wave + i;
    const int brow = 16 * c + (lane >> 2);
    const int bs   = (lane & 3) ^ ((brow >> 1) & 3);
    bSrc[i] = Wb + (size_t)brow * IN_F + bs * 8;
    bDst[i] = c * 1024;
  }

  f32x4 acc[4][4];
  #pragma unroll
  for (int m = 0; m < 4; ++m)
    #pragma unroll
    for (int n = 0; n < 4; ++n)
      acc[m][n] = (f32x4){0.f, 0.f, 0.f, 0.f};

  float ssq[4] = {0.f, 0.f, 0.f, 0.f};

  auto stageA = [&](int g) {      // logical group g -> physical (g+phg)&15
    const int pg = (g + phg) & 15;
    #pragma unroll
    for (int i = 0; i < 4; ++i)
      gload_lds16(aSrc[i] + pg * 64, Ab[g % 3] + aDst[i]);
  };
  auto stageB = [&](int kt) {     // logical step -> physical (kt+2*phg)&31
    const int pk = (kt + 2 * phg) & 31;
    #pragma unroll
    for (int i = 0; i < 2; ++i)
      gload_lds16(bSrc[i] + pk * 32, Bb[kt & 3] + bDst[i]);
  };

  // -------- prologue: A0(4), B0(2), A1(4), B1(2), B2(2) = 14 issued --------
  stageA(0);
  stageB(0);
  stageA(1);
  stageB(1);
  stageB(2);
  VM_WAIT(8);                    // retire A0+B0; A1,B1,B2 (8) in flight
  __builtin_amdgcn_s_barrier();

  // -------- main loop: 32 steps of BK=32 --------
  #pragma unroll
  for (int kt = 0; kt < NKT; ++kt) {
    if (kt + 3 < NKT) stageB(kt + 3);                         // 2 insts
    if ((kt & 1) == 0 && (kt / 2 + 2) < 16) stageA(kt / 2 + 2); // 4 insts

    const char* abuf = Ab[(kt >> 1) % 3];
    const char* bbuf = Bb[kt & 3];
    const int   gb   = (kt & 1) * 8 + 2 * q;   // A granule base within 256B row

    // A fragments (f32 -> bf16) + exact sumsq: 4 m-frags (rows wr*64+m*16+rm)
    bf16x8 aF[4];
    #pragma unroll
    for (int m = 0; m < 4; ++m) {
      const int ra = wr * 64 + m * 16 + rm;
      const char* ab = abuf + ra * 256;
      const int sw = ra & 7;
      const f32x4 lo = *reinterpret_cast<const f32x4*>(ab + ((gb)     ^ sw) * 16);
      const f32x4 hi = *reinterpret_cast<const f32x4*>(ab + ((gb + 1) ^ sw) * 16);
      ssq[m] += lo[0]*lo[0] + lo[1]*lo[1] + lo[2]*lo[2] + lo[3]*lo[3]
              + hi[0]*hi[0] + hi[1]*hi[1] + hi[2]*hi[2] + hi[3]*hi[3];
      bf16x8 a;
      a[0]=(__bf16)lo[0]; a[1]=(__bf16)lo[1]; a[2]=(__bf16)lo[2]; a[3]=(__bf16)lo[3];
      a[4]=(__bf16)hi[0]; a[5]=(__bf16)hi[1]; a[6]=(__bf16)hi[2]; a[7]=(__bf16)hi[3];
      aF[m] = a;
    }

    #pragma unroll
    for (int n = 0; n < 4; ++n) {
      const int rb = wc * 64 + n * 16 + rm;
      const bf16x8 bF = *reinterpret_cast<const bf16x8*>(
          bbuf + rb * 64 + (q ^ ((rb >> 1) & 3)) * 16);
      #pragma unroll
      for (int m = 0; m < 4; ++m)
        acc[m][n] = __builtin_amdgcn_mfma_f32_16x16x32_bf16(aF[m], bF, acc[m][n], 0, 0, 0);
    }

    // FIFO-simulated waits (each retires exactly the tiles step kt+1 needs):
    // kt=0 -> 8; odd steady -> 8; even 2..26 -> 12; 28 -> 8; 29 -> 2; >=30 -> 0.
    if (kt >= 30)                        { VM_WAIT(0); }
    else if (kt == 29)                   { VM_WAIT(2); }
    else if ((kt & 1) == 0 && kt >= 2 && kt <= 26) { VM_WAIT(12); }
    else                                 { VM_WAIT(8); }
    __builtin_amdgcn_s_barrier();
  }

  // -------- row L2-norms: reduce over the 4 q-groups --------
  #pragma unroll
  for (int m = 0; m < 4; ++m) {
    ssq[m] += __shfl_xor(ssq[m], 16);
    ssq[m] += __shfl_xor(ssq[m], 32);
  }
  float* norms = reinterpret_cast<float*>(smem + 163328);
  if (wc == 0 && q == 0) {
    #pragma unroll
    for (int m = 0; m < 4; ++m)
      norms[wr * 64 + m * 16 + rm] = 1.0f / (sqrtf(ssq[m]) + EPSV);
  }
  __syncthreads();

  // -------- scale + bias + relu -> LDS transpose --------
  float* stg = reinterpret_cast<float*>(smem);   // [128][260] f32 = 133120B
  const int col0 = wc * 64 + rm;
  #pragma unroll
  for (int n = 0; n < 4; ++n) {
    const float bn = bias[col0 + n * 16];
    #pragma unroll
    for (int m = 0; m < 4; ++m) {
      #pragma unroll
      for (int j = 0; j < 4; ++j) {
        const int lr = wr * 64 + m * 16 + q * 4 + j;
        stg[lr * 260 + col0 + n * 16] = fmaxf(acc[m][n][j] * norms[lr] + bn, 0.f);
      }
    }
  }
  __syncthreads();

  // -------- coalesced store: full 128B lines, 2 half-passes of 64 rows ----
  const int r = tid >> 3, p = tid & 7;       // 64 rows/pass, 8 threads/row
  #pragma unroll
  for (int half = 0; half < 2; ++half) {
    const int row = half * 64 + r;
    const float* srow = stg + row * 260;
    float* orow = out + (block_row + row) * OUT_F;
    #pragma unroll
    for (int i = 0; i < 8; ++i) {
      const int f = i * 8 + p;
      const f32x4 v = *reinterpret_cast<const f32x4*>(srow + f * 4);
      *reinterpret_cast<f32x4*>(orow + f * 4) = v;
    }
  }
}

extern "C" void kernel_launch(void* const* d_in, const int* in_sizes, int n_in,
                              void* d_out, int out_size, void* d_ws, size_t ws_size,
                              hipStream_t stream) {
  const float* x = (const float*)d_in[0];
  const float* W = (const float*)d_in[1];
  const float* b = (const float*)d_in[2];
  float* out = (float*)d_out;
  __bf16* Wb = (__bf16*)d_ws;   // 512 KB scratch

  wconv_kernel<<<(OUT_F * IN_F / 4) / 256, 256, 0, stream>>>(W, Wb);
  ffl_kernel<<<BATCH / BM, 512, 0, stream>>>(x, Wb, b, out);
}

// Round 10
// 172.564 us; speedup vs baseline: 1.0294x; 1.0294x over previous
//
#include <hip/hip_runtime.h>

// FFLayer: out = relu( (x / (||x||_2 + 1e-4)) @ W^T + b )
// x: [131072,1024] f32, W: [256,1024] f32, b: [256] f32, out: [131072,256] f32
//
// Round 10 = round 8 (best, 170.6us) with BK=64 compute steps: 16 barriers
// instead of 32 (fixed per-barrier ramp/skew amortized 2x). Staging layouts
// are r8's verbatim: A group = [128 rows][256B f32] granule-swizzled = one
// step's tile, 3-deep; B step-tile = 2 x r8's [256 rows][64B bf16] half-
// buffers, 2-deep. LDS = 3*32K + 2*32K = 160KB. Uniform counted waits:
// per step issue [Bh0,Bh1,A,A] -> vmcnt(2); prologue vmcnt(4); tail 0.

#define IN_F   1024
#define OUT_F  256
#define BATCH  131072
#define BM     128
#define NKT    16      // BK=64 compute steps
#define EPSV   1e-4f

typedef __attribute__((ext_vector_type(8))) __bf16 bf16x8;
typedef __attribute__((ext_vector_type(4))) __bf16 bf16x4;
typedef __attribute__((ext_vector_type(4))) float  f32x4;

__device__ __forceinline__ void gload_lds16(const void* g, void* lds) {
  __builtin_amdgcn_global_load_lds(
      (const __attribute__((address_space(1))) void*)g,
      (__attribute__((address_space(3))) void*)lds, 16, 0, 0);
}

#define VM_WAIT(N) do { asm volatile("s_waitcnt vmcnt(" #N ")" ::: "memory"); \
                        __builtin_amdgcn_sched_barrier(0); } while (0)

// W (f32 [256][1024]) -> bf16 [256][1024] in d_ws (512 KB)
__global__ void wconv_kernel(const float* __restrict__ W, __bf16* __restrict__ Wb) {
  const int t = blockIdx.x * blockDim.x + threadIdx.x;
  const float4 v = reinterpret_cast<const float4*>(W)[t];
  bf16x4 h;
  h[0] = (__bf16)v.x; h[1] = (__bf16)v.y; h[2] = (__bf16)v.z; h[3] = (__bf16)v.w;
  reinterpret_cast<bf16x4*>(Wb)[t] = h;
}

__global__ __launch_bounds__(1024, 4)
void ffl_kernel(const float* __restrict__ x, const __bf16* __restrict__ Wb,
                const float* __restrict__ bias, float* __restrict__ out) {
  // A bufs: 3 x 32KB at 0/32768/65536 (f32 [128 rows][256B], granule-swizzled)
  // B bufs: 2 x 32KB at 98304/131072; each = 2 halves of [256 rows][64B bf16]
  // norms: 512B at 163328 (tail of B[1], dead after the K-loop)
  // Epilogue stg [128][260] f32 = 133120B reuses [0,133120).
  __shared__ __align__(16) char smem[163840];
  char* const Ab[3] = {smem, smem + 32768, smem + 65536};
  char* const Bb[2] = {smem + 98304, smem + 131072};

  const int tid  = threadIdx.x;
  const int lane = tid & 63;
  const int wave = tid >> 6;     // 16 waves: 4(M) x 4(N), wave tile 32x64
  const int wr   = wave >> 2;
  const int wc   = wave & 3;
  const int rm   = lane & 15;
  const int q    = lane >> 4;
  const size_t block_row = (size_t)blockIdx.x * BM;
  const int phg = blockIdx.x & 15;            // K-rotation phase (BK=64 units)

  // ---- A staging: 2 issues/thread/step. Chunk c=2w+i (1KB = 4 rows x 256B).
  const float* aSrc[2]; int aDst[2];
  #pragma unroll
  for (int i = 0; i < 2; ++i) {
    const int c   = 2 * wave + i;
    const int row = 4 * c + (lane >> 4);
    const int s   = (lane & 15) ^ (row & 7);
    aSrc[i] = x + (block_row + row) * IN_F + s * 4;
    aDst[i] = c * 1024;
  }
  // ---- B staging: 2 issues/thread/step (one per 16KB half).
  //      Chunk = wave (1KB = 16 rows x 64B), r8's granule mapping.
  const int brow = 16 * wave + (lane >> 2);
  const int bs   = (lane & 3) ^ ((brow >> 1) & 3);
  const __bf16* bSrc = Wb + (size_t)brow * IN_F + bs * 8;   // +pg*64 +h*32
  const int bDst = wave * 1024;                              // +h*16384

  f32x4 acc[2][4];
  #pragma unroll
  for (int m = 0; m < 2; ++m)
    #pragma unroll
    for (int n = 0; n < 4; ++n)
      acc[m][n] = (f32x4){0.f, 0.f, 0.f, 0.f};

  float ssq0 = 0.f, ssq1 = 0.f;

  auto stageA = [&](int s) {      // logical step s -> physical (s+phg)&15
    const int pg = (s + phg) & 15;
    gload_lds16(aSrc[0] + pg * 64, Ab[s % 3] + aDst[0]);
    gload_lds16(aSrc[1] + pg * 64, Ab[s % 3] + aDst[1]);
  };
  auto stageB = [&](int s) {
    const int pg = (s + phg) & 15;
    gload_lds16(bSrc + pg * 64,      Bb[s & 1] + bDst);           // half 0
    gload_lds16(bSrc + pg * 64 + 32, Bb[s & 1] + 16384 + bDst);   // half 1
  };

  // -------- prologue: A(0) B(0) A(1) B(1) = 8 insts --------
  stageA(0);
  stageB(0);
  stageA(1);
  stageB(1);
  VM_WAIT(4);                    // A0,B0 landed; A1,B1 in flight
  __builtin_amdgcn_s_barrier();

  // -------- main loop: 16 steps of BK=64 --------
  #pragma unroll
  for (int kt = 0; kt < NKT; ++kt) {
    if (kt >= 1 && kt + 1 < NKT) stageB(kt + 1);   // 2 insts (B(1) pre-staged)
    if (kt + 2 < NKT) stageA(kt + 2);              // 2 insts

    const char* abuf = Ab[kt % 3];
    const char* bbuf = Bb[kt & 1];

    #pragma unroll
    for (int kk = 0; kk < 2; ++kk) {
      // A fragments for this 128B half (f32 -> bf16) + exact sumsq
      bf16x8 aF[2];
      #pragma unroll
      for (int m = 0; m < 2; ++m) {
        const int ra = wr * 32 + m * 16 + rm;
        const char* ab = abuf + ra * 256;
        const int sw = ra & 7;
        const int g0 = kk * 8 + 2 * q;     // granule (bit3 untouched by sw)
        const f32x4 lo = *reinterpret_cast<const f32x4*>(ab + ((g0)     ^ sw) * 16);
        const f32x4 hi = *reinterpret_cast<const f32x4*>(ab + ((g0 + 1) ^ sw) * 16);
        float& ssq = m ? ssq1 : ssq0;
        ssq += lo[0]*lo[0] + lo[1]*lo[1] + lo[2]*lo[2] + lo[3]*lo[3]
             + hi[0]*hi[0] + hi[1]*hi[1] + hi[2]*hi[2] + hi[3]*hi[3];
        bf16x8 a;
        a[0]=(__bf16)lo[0]; a[1]=(__bf16)lo[1]; a[2]=(__bf16)lo[2]; a[3]=(__bf16)lo[3];
        a[4]=(__bf16)hi[0]; a[5]=(__bf16)hi[1]; a[6]=(__bf16)hi[2]; a[7]=(__bf16)hi[3];
        aF[m] = a;
      }
      const char* bhalf = bbuf + kk * 16384;
      #pragma unroll
      for (int n = 0; n < 4; ++n) {
        const int rb = wc * 64 + n * 16 + rm;
        const bf16x8 bF = *reinterpret_cast<const bf16x8*>(
            bhalf + rb * 64 + (q ^ ((rb >> 1) & 3)) * 16);
        acc[0][n] = __builtin_amdgcn_mfma_f32_16x16x32_bf16(aF[0], bF, acc[0][n], 0, 0, 0);
        acc[1][n] = __builtin_amdgcn_mfma_f32_16x16x32_bf16(aF[1], bF, acc[1][n], 0, 0, 0);
      }
    }

    // FIFO waits: steady vmcnt(2) (retires B(kt+1), keeps A pair in flight);
    // kt>=14: nothing else needed in flight -> 0.
    if (kt < 14) { VM_WAIT(2); } else { VM_WAIT(0); }
    __builtin_amdgcn_s_barrier();
  }

  // -------- row L2-norms --------
  ssq0 += __shfl_xor(ssq0, 16); ssq0 += __shfl_xor(ssq0, 32);
  ssq1 += __shfl_xor(ssq1, 16); ssq1 += __shfl_xor(ssq1, 32);
  float* norms = reinterpret_cast<float*>(smem + 163328);
  if (wc == 0 && q == 0) {
    norms[wr * 32 + rm]      = 1.0f / (sqrtf(ssq0) + EPSV);
    norms[wr * 32 + 16 + rm] = 1.0f / (sqrtf(ssq1) + EPSV);
  }
  __syncthreads();

  // -------- scale + bias + relu -> LDS transpose --------
  float* stg = reinterpret_cast<float*>(smem);   // [128][260] f32 = 133120B
  const int col0 = wc * 64 + rm;
  #pragma unroll
  for (int n = 0; n < 4; ++n) {
    const float bn = bias[col0 + n * 16];
    #pragma unroll
    for (int m = 0; m < 2; ++m) {
      #pragma unroll
      for (int j = 0; j < 4; ++j) {
        const int lr = wr * 32 + m * 16 + q * 4 + j;
        stg[lr * 260 + col0 + n * 16] = fmaxf(acc[m][n][j] * norms[lr] + bn, 0.f);
      }
    }
  }
  __syncthreads();

  // -------- coalesced store: full 128B lines --------
  const int r = tid >> 3, p = tid & 7;       // 128 rows, 8 threads/row
  const float* srow = stg + r * 260;
  float* orow = out + (block_row + r) * OUT_F;
  #pragma unroll
  for (int i = 0; i < 8; ++i) {
    const int f = i * 8 + p;
    const f32x4 v = *reinterpret_cast<const f32x4*>(srow + f * 4);
    *reinterpret_cast<f32x4*>(orow + f * 4) = v;
  }
}

extern "C" void kernel_launch(void* const* d_in, const int* in_sizes, int n_in,
                              void* d_out, int out_size, void* d_ws, size_t ws_size,
                              hipStream_t stream) {
  const float* x = (const float*)d_in[0];
  const float* W = (const float*)d_in[1];
  const float* b = (const float*)d_in[2];
  float* out = (float*)d_out;
  __bf16* Wb = (__bf16*)d_ws;   // 512 KB scratch

  wconv_kernel<<<(OUT_F * IN_F / 4) / 256, 256, 0, stream>>>(W, Wb);
  ffl_kernel<<<BATCH / BM, 1024, 0, stream>>>(x, Wb, b, out);
}

// Round 12
// 169.853 us; speedup vs baseline: 1.0458x; 1.0160x over previous
//
#include <hip/hip_runtime.h>

// FFLayer: out = relu( (x / (||x||_2 + 1e-4)) @ W^T + b )
// x: [131072,1024] f32, W: [256,1024] f32, b: [256] f32, out: [131072,256] f32
//
// Round 12 = round 11's single-conversion A-path with a RACE-FREE pipeline:
//  A f32 3-deep (r8's proven flight: issue A(kt/2+2) at even kt), B 3-deep
//  (issue B(kt+2) every step). FIFO-simulated waits: prologue vmcnt(3),
//  steady vmcnt(3) EVERY step, tail 28/29 -> 1, >=30 -> 0. Each wait retires
//  exactly the tiles step kt+1 needs; nothing consumed while in flight.
//  phase-1: 1024 thr read f32 half-tile once (wave = 8 rows x 8 k-slots,
//  bank-uniform), exact ssq into regs, cvt once, write 8KB bf16 tile.
//  phase-2: MFMA waves read bf16 A frags + B frags.

#define IN_F   1024
#define OUT_F  256
#define BATCH  131072
#define BM     128
#define NKT    32      // BK=32 compute steps
#define EPSV   1e-4f

typedef __attribute__((ext_vector_type(8))) __bf16 bf16x8;
typedef __attribute__((ext_vector_type(4))) __bf16 bf16x4;
typedef __attribute__((ext_vector_type(4))) float  f32x4;

__device__ __forceinline__ void gload_lds16(const void* g, void* lds) {
  __builtin_amdgcn_global_load_lds(
      (const __attribute__((address_space(1))) void*)g,
      (__attribute__((address_space(3))) void*)lds, 16, 0, 0);
}

#define VM_WAIT(N) do { asm volatile("s_waitcnt vmcnt(" #N ")" ::: "memory"); \
                        __builtin_amdgcn_sched_barrier(0); } while (0)
#define MIDBAR()   do { asm volatile("s_waitcnt lgkmcnt(0)" ::: "memory"); \
                        __builtin_amdgcn_sched_barrier(0); \
                        __builtin_amdgcn_s_barrier(); } while (0)

// W (f32 [256][1024]) -> bf16 [256][1024] in d_ws (512 KB)
__global__ void wconv_kernel(const float* __restrict__ W, __bf16* __restrict__ Wb) {
  const int t = blockIdx.x * blockDim.x + threadIdx.x;
  const float4 v = reinterpret_cast<const float4*>(W)[t];
  bf16x4 h;
  h[0] = (__bf16)v.x; h[1] = (__bf16)v.y; h[2] = (__bf16)v.z; h[3] = (__bf16)v.w;
  reinterpret_cast<bf16x4*>(Wb)[t] = h;
}

__global__ __launch_bounds__(1024, 4)
void ffl_kernel(const float* __restrict__ x, const __bf16* __restrict__ Wb,
                const float* __restrict__ bias, float* __restrict__ out) {
  // LDS map:
  //   Af32  : 3 x 32KB  [0, 98304)          f32 [128][256B], src-swizzled
  //   Abf16 : 8KB       [98304, 106496)     bf16 [128][64B], swizzled
  //   Bb    : 3 x 16KB  [106496, 155648)    bf16 [256][64B], swizzled
  //   part  : 4KB       [155648, 159744)    ssq partials [8][128]
  //   norms : 512B      [159744, 160256)
  //   epilogue stg [128][260] f32 = 133120B reuses [0, 133120)
  __shared__ __align__(16) char smem[160256];
  char* const Ab[3] = {smem, smem + 32768, smem + 65536};
  char* const Abf   = smem + 98304;
  char* const Bb[3] = {smem + 106496, smem + 122880, smem + 139264};

  const int tid  = threadIdx.x;
  const int lane = tid & 63;
  const int wave = tid >> 6;     // 16 waves: 4(M) x 4(N), wave tile 32x64
  const int wr   = wave >> 2;
  const int wc   = wave & 3;
  const int rm   = lane & 15;
  const int q    = lane >> 4;
  const size_t block_row = (size_t)blockIdx.x * BM;
  const int phg = blockIdx.x & 15;            // K-rotation phase (A-groups)

  // ---- A staging: 2 issues/thread/group. Chunk c=2w+i (1KB = 4 rows x 256B).
  const float* aSrc[2]; int aDst[2];
  #pragma unroll
  for (int i = 0; i < 2; ++i) {
    const int c   = 2 * wave + i;
    const int row = 4 * c + (lane >> 4);
    const int s   = (lane & 15) ^ (row & 7);
    aSrc[i] = x + (block_row + row) * IN_F + s * 4;
    aDst[i] = c * 1024;
  }
  // ---- B staging: 1 issue/thread/step. Chunk = wave (1KB = 16 rows x 64B).
  const int brow = 16 * wave + (lane >> 2);
  const int bs   = (lane & 3) ^ ((brow >> 1) & 3);
  const __bf16* bSrc = Wb + (size_t)brow * IN_F + bs * 8;
  const int bDst = wave * 1024;

  // ---- phase-1 coords: wave covers 8 rows x 8 k-slots (bank-uniform)
  const int prow = 8 * wave + ((tid & 63) >> 3);   // 0..127
  const int pgs  = tid & 7;                        // 4-f32 slot within 128B
  const int p1_wr_byte = prow * 64 + (((pgs >> 1) ^ (prow & 3)) * 16) + (pgs & 1) * 8;

  f32x4 acc[2][4];
  #pragma unroll
  for (int m = 0; m < 2; ++m)
    #pragma unroll
    for (int n = 0; n < 4; ++n)
      acc[m][n] = (f32x4){0.f, 0.f, 0.f, 0.f};

  float pssq = 0.f;

  auto stageA = [&](int g) {      // logical group g -> physical (g+phg)&15
    const int pg = (g + phg) & 15;
    gload_lds16(aSrc[0] + pg * 64, Ab[g % 3] + aDst[0]);
    gload_lds16(aSrc[1] + pg * 64, Ab[g % 3] + aDst[1]);
  };
  auto stageB = [&](int kt) {     // logical step -> physical (kt+2*phg)&31
    const int pk = (kt + 2 * phg) & 31;
    gload_lds16(bSrc + pk * 32, Bb[kt % 3] + bDst);
  };

  // -------- prologue: A0(2) B0 A1(2) B1 = 6 issued --------
  stageA(0);
  stageB(0);
  stageA(1);
  stageB(1);
  VM_WAIT(3);                    // retire A0,B0; flight = [A1a A1b B1]
  __builtin_amdgcn_s_barrier();

  // -------- main loop: 32 steps of BK=32 --------
  #pragma unroll
  for (int kt = 0; kt < NKT; ++kt) {
    if (kt + 2 < NKT) stageB(kt + 2);                              // 1 inst
    if ((kt & 1) == 0 && (kt / 2 + 2) < 16) stageA(kt / 2 + 2);    // 2 insts

    // ---- phase 1: f32 tile -> ssq + bf16 tile (each element ONCE) ----
    {
      const char* abuf = Ab[(kt >> 1) % 3];
      const int sg = (kt & 1) * 8 + pgs;
      const f32x4 v = *reinterpret_cast<const f32x4*>(
          abuf + prow * 256 + ((sg ^ (prow & 7)) * 16));
      pssq += v[0]*v[0] + v[1]*v[1] + v[2]*v[2] + v[3]*v[3];
      bf16x4 hb;
      hb[0] = (__bf16)v[0]; hb[1] = (__bf16)v[1];
      hb[2] = (__bf16)v[2]; hb[3] = (__bf16)v[3];
      *reinterpret_cast<bf16x4*>(Abf + p1_wr_byte) = hb;
    }
    MIDBAR();

    // ---- phase 2: bf16 frags -> MFMA ----
    bf16x8 aF[2];
    #pragma unroll
    for (int m = 0; m < 2; ++m) {
      const int ra = wr * 32 + m * 16 + rm;
      aF[m] = *reinterpret_cast<const bf16x8*>(
          Abf + ra * 64 + ((q ^ (ra & 3)) * 16));
    }
    #pragma unroll
    for (int n = 0; n < 4; ++n) {
      const int rb = wc * 64 + n * 16 + rm;
      const bf16x8 bF = *reinterpret_cast<const bf16x8*>(
          Bb[kt % 3] + rb * 64 + ((q ^ ((rb >> 1) & 3)) * 16));
      acc[0][n] = __builtin_amdgcn_mfma_f32_16x16x32_bf16(aF[0], bF, acc[0][n], 0, 0, 0);
      acc[1][n] = __builtin_amdgcn_mfma_f32_16x16x32_bf16(aF[1], bF, acc[1][n], 0, 0, 0);
    }

    // FIFO-simulated waits (retire exactly what step kt+1 needs):
    if (kt <= 27)      { VM_WAIT(3); }
    else if (kt <= 29) { VM_WAIT(1); }
    else               { VM_WAIT(0); }
    __builtin_amdgcn_s_barrier();
  }

  // -------- row L2-norms: partials -> LDS reduce --------
  float* partials = reinterpret_cast<float*>(smem + 155648);
  partials[pgs * 128 + prow] = pssq;
  __syncthreads();
  float* norms = reinterpret_cast<float*>(smem + 159744);
  if (tid < 128) {
    float s = 0.f;
    #pragma unroll
    for (int g = 0; g < 8; ++g) s += partials[g * 128 + tid];
    norms[tid] = 1.0f / (sqrtf(s) + EPSV);
  }
  __syncthreads();

  // -------- scale + bias + relu -> LDS transpose --------
  float* stg = reinterpret_cast<float*>(smem);   // [128][260] f32 = 133120B
  const int col0 = wc * 64 + rm;
  #pragma unroll
  for (int n = 0; n < 4; ++n) {
    const float bn = bias[col0 + n * 16];
    #pragma unroll
    for (int m = 0; m < 2; ++m) {
      #pragma unroll
      for (int j = 0; j < 4; ++j) {
        const int lr = wr * 32 + m * 16 + q * 4 + j;
        stg[lr * 260 + col0 + n * 16] = fmaxf(acc[m][n][j] * norms[lr] + bn, 0.f);
      }
    }
  }
  __syncthreads();

  // -------- coalesced store: full 128B lines --------
  const int r = tid >> 3, p = tid & 7;       // 128 rows, 8 threads/row
  const float* srow = stg + r * 260;
  float* orow = out + (block_row + r) * OUT_F;
  #pragma unroll
  for (int i = 0; i < 8; ++i) {
    const int f = i * 8 + p;
    const f32x4 v = *reinterpret_cast<const f32x4*>(srow + f * 4);
    *reinterpret_cast<f32x4*>(orow + f * 4) = v;
  }
}

extern "C" void kernel_launch(void* const* d_in, const int* in_sizes, int n_in,
                              void* d_out, int out_size, void* d_ws, size_t ws_size,
                              hipStream_t stream) {
  const float* x = (const float*)d_in[0];
  const float* W = (const float*)d_in[1];
  const float* b = (const float*)d_in[2];
  float* out = (float*)d_out;
  __bf16* Wb = (__bf16*)d_ws;   // 512 KB scratch

  wconv_kernel<<<(OUT_F * IN_F / 4) / 256, 256, 0, stream>>>(W, Wb);
  ffl_kernel<<<BATCH / BM, 1024, 0, stream>>>(x, Wb, b, out);
}